// Round 15
// baseline (248.906 us; speedup 1.0000x reference)
//
#include <hip/hip_runtime.h>
#include <hip/hip_bf16.h>

// ---------------------------------------------------------------------------
// 2-layer GAT (PyG GATConv, concat=False -> head mean, self-loops).
// Round 15 (on R14's 208.9us direct-slot structure):
//  - fill: 4 edges/thread, all 4 returning atomics issued before any
//    dependent slot store (tests whether the ~15G/s atomic ceiling is
//    MLP-bound or fabric-bound).
//  - gathers: __launch_bounds__(256,6) -> occupancy cap 50%->75% (VGPR cap
//    ~85, gather uses ~52; NOT 8/64-cap which would respill like R9).
// ---------------------------------------------------------------------------

typedef short v8s __attribute__((ext_vector_type(8)));
typedef float v4f __attribute__((ext_vector_type(4)));
typedef float v2f __attribute__((ext_vector_type(2)));

template <int K> struct IC { static constexpr int value = K; };

constexpr int MAXD = 128;  // slots per node (Poisson(32): P(>=128) ~ 1e-40)

__device__ __forceinline__ void bf2x(unsigned int u, float& lo, float& hi) {
    union { unsigned int i; float f; } a, b;
    a.i = u << 16;
    b.i = u & 0xffff0000u;
    lo = a.f;
    hi = b.f;
}
__device__ __forceinline__ v2f bf2p(unsigned int u) {
    union { unsigned int i; float f; } a, b;
    a.i = u << 16;
    b.i = u & 0xffff0000u;
    return (v2f){a.f, b.f};
}
__device__ __forceinline__ unsigned short f2bf(float f) {
    union { float f; unsigned int i; } v;
    v.f = f;
    unsigned int lsb = (v.i >> 16) & 1u;
    v.i += 0x7fffu + lsb;  // RNE (finite values only)
    return (unsigned short)(v.i >> 16);
}
__device__ __forceinline__ unsigned int pack2(float a, float b) {
    return (unsigned int)f2bf(a) | ((unsigned int)f2bf(b) << 16);
}

// ---------------------------- fused prep -----------------------------------
// Roles by blockIdx range: [0,Bcast) cast x; +256 Bt1; +64 Bt2; +2 aw1;
// +1 aw2; +Bzero init cnt=1/slot self-loop + zero as2/ad2.
__global__ void fused_prep_kernel(const float* __restrict__ x,
                                  const float* __restrict__ W1, const float* __restrict__ W2,
                                  const float* __restrict__ as1v, const float* __restrict__ ad1v,
                                  const float* __restrict__ as2v, const float* __restrict__ ad2v,
                                  unsigned short* __restrict__ xb,
                                  unsigned short* __restrict__ Bt1,
                                  unsigned short* __restrict__ Bt2,
                                  float* __restrict__ wsrc1, float* __restrict__ wdst1,
                                  float* __restrict__ wsrc2, float* __restrict__ wdst2,
                                  int* __restrict__ cnt, int* __restrict__ slot,
                                  float* __restrict__ as2, float* __restrict__ ad2, int N) {
    const int Bcast = (N * 32 + 255) / 256;  // N*128/4 float4s
    int b = blockIdx.x;
    if (b < Bcast) {  // cast x -> bf16
        int i = (b * 256 + threadIdx.x) * 4;
        if (i + 3 < N * 128) {
            float4 v = *(const float4*)&x[i];
            ushort4 o;
            o.x = f2bf(v.x);
            o.y = f2bf(v.y);
            o.z = f2bf(v.z);
            o.w = f2bf(v.w);
            *(ushort4*)&xb[i] = o;
        } else {
            for (; i < N * 128; ++i) xb[i] = f2bf(x[i]);
        }
        return;
    }
    b -= Bcast;
    if (b < 256) {  // Bt1[c][h*128+k] = W1[k][h*128+c] * 0.25
        int i = b * 256 + threadIdx.x;
        int c = i >> 9;
        int r = i & 511;
        int h = r >> 7, k = r & 127;
        Bt1[i] = f2bf(W1[(size_t)k * 512 + (h << 7) + c] * 0.25f);
        return;
    }
    b -= 256;
    if (b < 64) {  // Bt2[c][k] = W2[k][c]
        int i = b * 256 + threadIdx.x;
        int c = i >> 7, k = i & 127;
        Bt2[i] = f2bf(W2[(size_t)k * 128 + c]);
        return;
    }
    b -= 64;
    if (b < 2) {  // wsrc1/wdst1[h*128+k] = <W1[k][h*128+:], a_{s,d}1[h][:]>
        int i = b * 256 + threadIdx.x;
        int h = i >> 7, k = i & 127;
        const float* wr = W1 + (size_t)k * 512 + (h << 7);
        const float* as_ = as1v + (h << 7);
        const float* ad_ = ad1v + (h << 7);
        float s1 = 0.f, s2 = 0.f;
        for (int c = 0; c < 128; ++c) {
            float wv = wr[c];
            s1 += wv * as_[c];
            s2 += wv * ad_[c];
        }
        wsrc1[i] = s1;
        wdst1[i] = s2;
        return;
    }
    b -= 2;
    if (b < 1) {  // wsrc2/wdst2
        int k = threadIdx.x;
        if (k < 128) {
            const float* wr = W2 + (size_t)k * 128;
            float s1 = 0.f, s2 = 0.f;
            for (int c = 0; c < 128; ++c) {
                float wv = wr[c];
                s1 += wv * as2v[c];
                s2 += wv * ad2v[c];
            }
            wsrc2[k] = s1;
            wdst2[k] = s2;
        }
        return;
    }
    b -= 1;
    {  // init cnt=1 (self-loop), slot head = self, zero as2/ad2
        int i = b * 256 + threadIdx.x;
        if (i < N) {
            cnt[i] = 1;
            slot[(size_t)i * MAXD] = i;
            as2[i] = 0.f;
            ad2[i] = 0.f;
        }
    }
}

// ---------------------- fused fill + alpha1 --------------------------------
// Blocks [0,Bfill): direct-slot fill, 4 edges/thread; all 4 returning
// atomics issued before any dependent store (max atomic MLP).
// Blocks [Bfill,...): alpha1 per node (1 wave/node, 4/block).
__launch_bounds__(256)
__global__ void fill_alpha_kernel(const int* __restrict__ src, const int* __restrict__ dst,
                                  int* __restrict__ cnt, int* __restrict__ slot, int E,
                                  const unsigned int* __restrict__ xrow,  // [N,64]
                                  const float* __restrict__ wsrc, const float* __restrict__ wdst,
                                  float* __restrict__ asrc, float* __restrict__ adst, int N,
                                  int Bfill) {
    if ((int)blockIdx.x < Bfill) {
        int i = (blockIdx.x * 256 + threadIdx.x) * 4;
        if (i + 3 < E) {
            int4 s4 = *(const int4*)&src[i];
            int4 d4 = *(const int4*)&dst[i];
            int p0 = atomicAdd(&cnt[d4.x], 1);
            int p1 = atomicAdd(&cnt[d4.y], 1);
            int p2 = atomicAdd(&cnt[d4.z], 1);
            int p3 = atomicAdd(&cnt[d4.w], 1);
            if (p0 < MAXD) slot[(size_t)d4.x * MAXD + p0] = s4.x;
            if (p1 < MAXD) slot[(size_t)d4.y * MAXD + p1] = s4.y;
            if (p2 < MAXD) slot[(size_t)d4.z * MAXD + p2] = s4.z;
            if (p3 < MAXD) slot[(size_t)d4.w * MAXD + p3] = s4.w;
        } else {
            for (; i < E; ++i) {
                int d = dst[i];
                int pos = atomicAdd(&cnt[d], 1);
                if (pos < MAXD) slot[(size_t)d * MAXD + pos] = src[i];
            }
        }
        return;
    }
    // ---- alpha1 (H=4) ----
    constexpr int H = 4;
    __shared__ float s_wv[2 * H * 128];
    for (int i = threadIdx.x; i < 2 * H * 128; i += 256)
        s_wv[i] = (i < H * 128) ? wsrc[i] : wdst[i - H * 128];
    __syncthreads();
    const int wid = threadIdx.x >> 6, lane = threadIdx.x & 63;
    const int n = (blockIdx.x - Bfill) * 4 + wid;
    if (n >= N) return;
    unsigned int u = xrow[(size_t)n * 64 + lane];
    float f0, f1;
    bf2x(u, f0, f1);
    float s1[H], s2[H];
#pragma unroll
    for (int h = 0; h < H; ++h) {
        float2 ws = *(const float2*)&s_wv[h * 128 + 2 * lane];
        float2 wd = *(const float2*)&s_wv[H * 128 + h * 128 + 2 * lane];
        s1[h] = f0 * ws.x + f1 * ws.y;
        s2[h] = f0 * wd.x + f1 * wd.y;
    }
#pragma unroll
    for (int off = 32; off; off >>= 1)
#pragma unroll
        for (int h = 0; h < H; ++h) {
            s1[h] += __shfl_xor(s1[h], off);
            s2[h] += __shfl_xor(s2[h], off);
        }
    if (lane == 0) {
#pragma unroll
        for (int h = 0; h < H; ++h) {
            asrc[(size_t)n * H + h] = s1[h];
            adst[(size_t)n * H + h] = s2[h];
        }
    }
}

// ---------------------------- x-space gather -------------------------------
// One wave per destination node; edges in slot[n*MAXD .. n*MAXD+deg).
// Quarter-wave (16 lanes x 16B) per 256B row: 4 edges per VMEM inst. Full
// batches = 8 k-iters (32 edges, 8KB in flight); tail via switch(kmax).
// float2 accumulation -> v_pk_fma_f32. launch_bounds(256,6): 75% occ cap,
// VGPR cap ~85 (kernel uses ~52 -> no spill).
template <int H, int NPB>
__launch_bounds__(64 * NPB, 6)
__global__ void gat_gather_kernel(const uint4* __restrict__ xrow4,  // [N,16]
                                  const float* __restrict__ asrc,   // [N*H]
                                  const float* __restrict__ adst,   // [N*H]
                                  const int* __restrict__ cnt,      // [N] final degrees
                                  const int* __restrict__ slot,     // [N*MAXD]
                                  uint4* __restrict__ Sb4,          // [N, H*16]
                                  int N) {
    static_assert(H == 4 || H == 1, "H");
    const int wid = threadIdx.x >> 6, lane = threadIdx.x & 63;
    const int q = lane >> 4, l16 = lane & 15;
    const int n = blockIdx.x * NPB + wid;
    if (n >= N) return;

    __shared__ int s_src_all[NPB][64];
    __shared__ float s_w_all[NPB][64 * H];
    int* s_src = s_src_all[wid];
    float* s_w = s_w_all[wid];

    const int base = n * MAXD;
    const int deg = min(cnt[n], MAXD);  // >= 1 (self-loop)

    float adst_n[H];
#pragma unroll
    for (int h = 0; h < H; ++h) adst_n[h] = adst[(size_t)n * H + h];

    float sum_h[H] = {};
    v2f acc[4 * H];  // acc[h*4+j] = channels (l16*8+2j, +1), quarter-partial
#pragma unroll
    for (int i = 0; i < 4 * H; ++i) acc[i] = (v2f){0.f, 0.f};

    // batched gather body: KK k-iters, loads clustered before consumes.
    auto do_batch = [&](int j0, auto kc) {
        constexpr int KK = decltype(kc)::value;
        int ss[KK];
        uint4 d[KK];
#pragma unroll
        for (int k = 0; k < KK; ++k) ss[k] = s_src[j0 + k * 4 + q];
#pragma unroll
        for (int k = 0; k < KK; ++k) d[k] = xrow4[(size_t)ss[k] * 16 + l16];
#pragma unroll
        for (int k = 0; k < KK; ++k) {
            v2f f2[4];
            f2[0] = bf2p(d[k].x);
            f2[1] = bf2p(d[k].y);
            f2[2] = bf2p(d[k].z);
            f2[3] = bf2p(d[k].w);
            if constexpr (H == 4) {
                float4 w = *(const float4*)&s_w[(j0 + k * 4 + q) * 4];
                v2f w0 = (v2f){w.x, w.x}, w1 = (v2f){w.y, w.y};
                v2f w2 = (v2f){w.z, w.z}, w3 = (v2f){w.w, w.w};
#pragma unroll
                for (int j = 0; j < 4; ++j) {
                    acc[j] += w0 * f2[j];
                    acc[4 + j] += w1 * f2[j];
                    acc[8 + j] += w2 * f2[j];
                    acc[12 + j] += w3 * f2[j];
                }
            } else {
                float w = s_w[j0 + k * 4 + q];
                v2f w0 = (v2f){w, w};
#pragma unroll
                for (int j = 0; j < 4; ++j) acc[j] += w0 * f2[j];
            }
        }
    };

    for (int i0 = 0; i0 < deg; i0 += 64) {
        const int cntc = min(64, deg - i0);
        {  // branch-free prep: pad lanes use clamped source with weight 0
            const bool valid = lane < cntc;
            int idx = i0 + (valid ? lane : (cntc - 1));
            int s = slot[base + idx];
            s_src[lane] = s;
            if constexpr (H == 4) {
                float4 av = ((const float4*)asrc)[s];
                float ev[4] = {av.x, av.y, av.z, av.w};
#pragma unroll
                for (int hh = 0; hh < 4; ++hh) {
                    float e = ev[hh] + adst_n[hh];
                    e = e > 0.f ? e : 0.2f * e;
                    float wv = valid ? __expf(e) : 0.f;
                    s_w[lane * 4 + hh] = wv;
                    sum_h[hh] += wv;
                }
            } else {
                float e = asrc[s] + adst_n[0];
                e = e > 0.f ? e : 0.2f * e;
                float wv = valid ? __expf(e) : 0.f;
                s_w[lane] = wv;
                sum_h[0] += wv;
            }
        }
        __threadfence_block();  // drain LDS writes (same-wave cross-lane read)

        int j0 = 0;
        for (; j0 + 32 <= cntc; j0 += 32) do_batch(j0, IC<8>{});
        const int rem = cntc - j0;
        if (rem > 0) {
            // wave-uniform kmax; slots [cntc, j0+4*kmax) have weight 0 from prep
            switch ((rem + 3) >> 2) {
                case 1: do_batch(j0, IC<1>{}); break;
                case 2: do_batch(j0, IC<2>{}); break;
                case 3: do_batch(j0, IC<3>{}); break;
                case 4: do_batch(j0, IC<4>{}); break;
                case 5: do_batch(j0, IC<5>{}); break;
                case 6: do_batch(j0, IC<6>{}); break;
                case 7: do_batch(j0, IC<7>{}); break;
                default: do_batch(j0, IC<8>{}); break;
            }
        }
    }

    // cross-quarter reduce (lanes sharing l16): xor 16, 32
#pragma unroll
    for (int i = 0; i < 4 * H; ++i) {
        acc[i][0] += __shfl_xor(acc[i][0], 16);
        acc[i][1] += __shfl_xor(acc[i][1], 16);
        acc[i][0] += __shfl_xor(acc[i][0], 32);
        acc[i][1] += __shfl_xor(acc[i][1], 32);
    }
    // denominator full-wave reduce
#pragma unroll
    for (int off = 32; off; off >>= 1)
#pragma unroll
        for (int h = 0; h < H; ++h) sum_h[h] += __shfl_xor(sum_h[h], off);

    if constexpr (H == 4) {
#pragma unroll
        for (int h = 0; h < 4; ++h) {
            if (q == h) {  // quarter h writes head h (constant reg indices)
                float rd = 1.0f / sum_h[h];
                uint4 o;
                o.x = pack2(acc[h * 4 + 0][0] * rd, acc[h * 4 + 0][1] * rd);
                o.y = pack2(acc[h * 4 + 1][0] * rd, acc[h * 4 + 1][1] * rd);
                o.z = pack2(acc[h * 4 + 2][0] * rd, acc[h * 4 + 2][1] * rd);
                o.w = pack2(acc[h * 4 + 3][0] * rd, acc[h * 4 + 3][1] * rd);
                Sb4[(size_t)n * 64 + h * 16 + l16] = o;
            }
        }
    } else {
        if (q == 0) {
            float rd = 1.0f / sum_h[0];
            uint4 o;
            o.x = pack2(acc[0][0] * rd, acc[0][1] * rd);
            o.y = pack2(acc[1][0] * rd, acc[1][1] * rd);
            o.z = pack2(acc[2][0] * rd, acc[2][1] * rd);
            o.w = pack2(acc[3][0] * rd, acc[3][1] * rd);
            Sb4[(size_t)n * 16 + l16] = o;
        }
    }
}

// ---------------------------- MFMA GEMM + bias + act -----------------------
__device__ __forceinline__ void store_out(float* p, float v) { *p = v; }
__device__ __forceinline__ void store_out(unsigned short* p, float v) { *p = f2bf(v); }

// C = act(A @ Bt^T + bias). If FUSE_A2: also accumulate per-row dots
// as2[row] += sum_col val*ws2[col], ad2 likewise (alpha2 fused into gemm1).
template <typename OT, bool ELU, bool FUSE_A2>
__launch_bounds__(256)
__global__ void gemm_bias_act_kernel(const unsigned short* __restrict__ A,
                                     const unsigned short* __restrict__ Bt,
                                     const float* __restrict__ bias,
                                     OT* __restrict__ C,
                                     const float* __restrict__ ws2,
                                     const float* __restrict__ wd2,
                                     float* __restrict__ as2, float* __restrict__ ad2,
                                     int M, int Nout, int K) {
    constexpr int BK = 32;
    __shared__ unsigned short As[64][40];
    __shared__ unsigned short Bs[64][40];

    const int tid = threadIdx.x;
    const int w = tid >> 6;
    const int lane = tid & 63;
    const int m16 = lane & 15;
    const int kg = lane >> 4;
    const int m0 = blockIdx.y * 64;
    const int n0 = blockIdx.x * 64;

    v4f acc[4];
#pragma unroll
    for (int i = 0; i < 4; ++i) acc[i] = (v4f){0.f, 0.f, 0.f, 0.f};

    const int srow = tid >> 2;
    const int sseg = tid & 3;
    const int arow_g = min(m0 + srow, M - 1);  // clamp; tail rows never stored
    const unsigned short* Ap = &A[(size_t)arow_g * K + sseg * 8];
    const unsigned short* Bp = &Bt[(size_t)(n0 + srow) * K + sseg * 8];

    for (int k0 = 0; k0 < K; k0 += BK) {
        uint4 av = *(const uint4*)(Ap + k0);
        uint4 bv = *(const uint4*)(Bp + k0);
        __syncthreads();
        *(uint4*)&As[srow][sseg * 8] = av;
        *(uint4*)&Bs[srow][sseg * 8] = bv;
        __syncthreads();
        v8s a = *(const v8s*)&As[w * 16 + m16][kg * 8];
#pragma unroll
        for (int i = 0; i < 4; ++i) {
            v8s b = *(const v8s*)&Bs[i * 16 + m16][kg * 8];
            acc[i] = __builtin_amdgcn_mfma_f32_16x16x32_bf16(a, b, acc[i], 0, 0, 0);
        }
    }

    float pr_s[4] = {}, pr_d[4] = {};
#pragma unroll
    for (int i = 0; i < 4; ++i) {
        const int col = n0 + i * 16 + m16;
        const float bv = bias[col];
        float w2s = 0.f, w2d = 0.f;
        if constexpr (FUSE_A2) {
            w2s = ws2[col];
            w2d = wd2[col];
        }
#pragma unroll
        for (int r = 0; r < 4; ++r) {
            int row = m0 + w * 16 + kg * 4 + r;
            if (row < M) {
                float val = acc[i][r] + bv;
                if constexpr (ELU) val = val > 0.f ? val : (__expf(val) - 1.0f);
                store_out(&C[(size_t)row * Nout + col], val);
                if constexpr (FUSE_A2) {
                    pr_s[r] += val * w2s;
                    pr_d[r] += val * w2d;
                }
            }
        }
    }
    if constexpr (FUSE_A2) {
        // reduce across the 16 lanes sharing a row (m16 axis, within quarter)
#pragma unroll
        for (int off = 1; off < 16; off <<= 1)
#pragma unroll
            for (int r = 0; r < 4; ++r) {
                pr_s[r] += __shfl_xor(pr_s[r], off);
                pr_d[r] += __shfl_xor(pr_d[r], off);
            }
        if (m16 == 0) {
#pragma unroll
            for (int r = 0; r < 4; ++r) {
                int row = m0 + w * 16 + kg * 4 + r;
                if (row < M) {
                    atomicAdd(&as2[row], pr_s[r]);
                    atomicAdd(&ad2[row], pr_d[r]);
                }
            }
        }
    }
}

// ---------------------------------------------------------------------------

extern "C" void kernel_launch(void* const* d_in, const int* in_sizes, int n_in,
                              void* d_out, int out_size, void* d_ws, size_t ws_size,
                              hipStream_t stream) {
    const float* x = (const float*)d_in[0];
    const float* W1 = (const float*)d_in[1];
    const float* a_src1 = (const float*)d_in[2];
    const float* a_dst1 = (const float*)d_in[3];
    const float* b1 = (const float*)d_in[4];
    const float* W2 = (const float*)d_in[5];
    const float* a_src2 = (const float*)d_in[6];
    const float* a_dst2 = (const float*)d_in[7];
    const float* b2 = (const float*)d_in[8];
    const int* edge = (const int*)d_in[9];
    float* out = (float*)d_out;

    constexpr int F = 128, H = 4;
    const int N = in_sizes[0] / F;  // 20000
    const int E = in_sizes[9] / 2;  // 640000

    char* ws = (char*)d_ws;
    size_t o = 0;
    auto take = [&](size_t bytes) {
        char* p = ws + o;
        o = (o + bytes + 255) & ~(size_t)255;
        return p;
    };
    int* cnt = (int*)take((size_t)N * 4);
    int* slot = (int*)take((size_t)N * MAXD * 4);                       // 10.2 MB
    unsigned short* xb = (unsigned short*)take((size_t)N * F * 2);      // bf16 x
    unsigned short* Bt1 = (unsigned short*)take((size_t)F * H * F * 2); // [128][512]
    unsigned short* Bt2 = (unsigned short*)take((size_t)F * F * 2);     // [128][128]
    float* wsrc1 = (float*)take((size_t)H * F * 4);
    float* wdst1 = (float*)take((size_t)H * F * 4);
    float* wsrc2 = (float*)take((size_t)F * 4);
    float* wdst2 = (float*)take((size_t)F * 4);
    float* as1 = (float*)take((size_t)N * H * 4);
    float* ad1 = (float*)take((size_t)N * H * 4);
    unsigned short* Sb1 = (unsigned short*)take((size_t)N * H * F * 2);  // [N,512] bf16
    unsigned short* h2b = (unsigned short*)take((size_t)N * F * 2);      // layer-1 out, bf16
    float* as2 = (float*)take((size_t)N * 4);
    float* ad2 = (float*)take((size_t)N * 4);
    unsigned short* S2b = (unsigned short*)take((size_t)N * F * 2);      // [N,128] bf16
    (void)ws_size;

    const int* esrc = edge;
    const int* edst = edge + E;

    // ---- fused prep (casts, weight transforms, cnt=1/self-loop, zero a2) ----
    const int Bcast = (N * 32 + 255) / 256;
    const int Bzero = (N + 255) / 256;
    hipLaunchKernelGGL(fused_prep_kernel, dim3(Bcast + 256 + 64 + 2 + 1 + Bzero), dim3(256), 0,
                       stream, x, W1, W2, a_src1, a_dst1, a_src2, a_dst2, xb, Bt1, Bt2, wsrc1,
                       wdst1, wsrc2, wdst2, cnt, slot, as2, ad2, N);

    // ---- fused direct-slot fill (4 edges/thread) + alpha1 ----
    const int Bfill = (E / 4 + 255) / 256;
    const int Balpha = (N + 3) / 4;
    hipLaunchKernelGGL(fill_alpha_kernel, dim3(Bfill + Balpha), dim3(256), 0, stream, esrc, edst,
                       cnt, slot, E, (const unsigned int*)xb, wsrc1, wdst1, as1, ad1, N, Bfill);

    // ---- layer 1: gather + gemm (alpha2 fused into epilogue) ----
    hipLaunchKernelGGL((gat_gather_kernel<H, 4>), dim3((N + 3) / 4), dim3(256), 0, stream,
                       (const uint4*)xb, as1, ad1, cnt, slot, (uint4*)Sb1, N);
    hipLaunchKernelGGL((gemm_bias_act_kernel<unsigned short, true, true>),
                       dim3(F / 64, (N + 63) / 64), dim3(256), 0, stream, Sb1, Bt1, b1, h2b,
                       wsrc2, wdst2, as2, ad2, N, F, H * F);

    // ---- layer 2: gather + gemm ----
    hipLaunchKernelGGL((gat_gather_kernel<1, 4>), dim3((N + 3) / 4), dim3(256), 0, stream,
                       (const uint4*)h2b, as2, ad2, cnt, slot, (uint4*)S2b, N);
    hipLaunchKernelGGL((gemm_bias_act_kernel<float, true, false>), dim3(F / 64, (N + 63) / 64),
                       dim3(256), 0, stream, S2b, Bt2, b2, out, nullptr, nullptr, nullptr,
                       nullptr, N, F, F);
}

// Round 16
// 207.861 us; speedup vs baseline: 1.1975x; 1.1975x over previous
//
#include <hip/hip_runtime.h>
#include <hip/hip_bf16.h>

// ---------------------------------------------------------------------------
// 2-layer GAT (PyG GATConv, concat=False -> head mean, self-loops).
// Round 16: revert R15's occupancy hint. (256,6) forced VGPR 52->40 and
// spilled the gather batch (WRITE 175MB vs 20MB true output) -- the R9
// failure mode induced by the hint. Gathers back to the proven (256,4)
// (R14: 208.9us). Keep R15's 4-edge/thread fill (neutral-or-better).
// ---------------------------------------------------------------------------

typedef short v8s __attribute__((ext_vector_type(8)));
typedef float v4f __attribute__((ext_vector_type(4)));
typedef float v2f __attribute__((ext_vector_type(2)));

template <int K> struct IC { static constexpr int value = K; };

constexpr int MAXD = 128;  // slots per node (Poisson(32): P(>=128) ~ 1e-40)

__device__ __forceinline__ void bf2x(unsigned int u, float& lo, float& hi) {
    union { unsigned int i; float f; } a, b;
    a.i = u << 16;
    b.i = u & 0xffff0000u;
    lo = a.f;
    hi = b.f;
}
__device__ __forceinline__ v2f bf2p(unsigned int u) {
    union { unsigned int i; float f; } a, b;
    a.i = u << 16;
    b.i = u & 0xffff0000u;
    return (v2f){a.f, b.f};
}
__device__ __forceinline__ unsigned short f2bf(float f) {
    union { float f; unsigned int i; } v;
    v.f = f;
    unsigned int lsb = (v.i >> 16) & 1u;
    v.i += 0x7fffu + lsb;  // RNE (finite values only)
    return (unsigned short)(v.i >> 16);
}
__device__ __forceinline__ unsigned int pack2(float a, float b) {
    return (unsigned int)f2bf(a) | ((unsigned int)f2bf(b) << 16);
}

// ---------------------------- fused prep -----------------------------------
// Roles by blockIdx range: [0,Bcast) cast x; +256 Bt1; +64 Bt2; +2 aw1;
// +1 aw2; +Bzero init cnt=1/slot self-loop + zero as2/ad2.
__global__ void fused_prep_kernel(const float* __restrict__ x,
                                  const float* __restrict__ W1, const float* __restrict__ W2,
                                  const float* __restrict__ as1v, const float* __restrict__ ad1v,
                                  const float* __restrict__ as2v, const float* __restrict__ ad2v,
                                  unsigned short* __restrict__ xb,
                                  unsigned short* __restrict__ Bt1,
                                  unsigned short* __restrict__ Bt2,
                                  float* __restrict__ wsrc1, float* __restrict__ wdst1,
                                  float* __restrict__ wsrc2, float* __restrict__ wdst2,
                                  int* __restrict__ cnt, int* __restrict__ slot,
                                  float* __restrict__ as2, float* __restrict__ ad2, int N) {
    const int Bcast = (N * 32 + 255) / 256;  // N*128/4 float4s
    int b = blockIdx.x;
    if (b < Bcast) {  // cast x -> bf16
        int i = (b * 256 + threadIdx.x) * 4;
        if (i + 3 < N * 128) {
            float4 v = *(const float4*)&x[i];
            ushort4 o;
            o.x = f2bf(v.x);
            o.y = f2bf(v.y);
            o.z = f2bf(v.z);
            o.w = f2bf(v.w);
            *(ushort4*)&xb[i] = o;
        } else {
            for (; i < N * 128; ++i) xb[i] = f2bf(x[i]);
        }
        return;
    }
    b -= Bcast;
    if (b < 256) {  // Bt1[c][h*128+k] = W1[k][h*128+c] * 0.25
        int i = b * 256 + threadIdx.x;
        int c = i >> 9;
        int r = i & 511;
        int h = r >> 7, k = r & 127;
        Bt1[i] = f2bf(W1[(size_t)k * 512 + (h << 7) + c] * 0.25f);
        return;
    }
    b -= 256;
    if (b < 64) {  // Bt2[c][k] = W2[k][c]
        int i = b * 256 + threadIdx.x;
        int c = i >> 7, k = i & 127;
        Bt2[i] = f2bf(W2[(size_t)k * 128 + c]);
        return;
    }
    b -= 64;
    if (b < 2) {  // wsrc1/wdst1[h*128+k] = <W1[k][h*128+:], a_{s,d}1[h][:]>
        int i = b * 256 + threadIdx.x;
        int h = i >> 7, k = i & 127;
        const float* wr = W1 + (size_t)k * 512 + (h << 7);
        const float* as_ = as1v + (h << 7);
        const float* ad_ = ad1v + (h << 7);
        float s1 = 0.f, s2 = 0.f;
        for (int c = 0; c < 128; ++c) {
            float wv = wr[c];
            s1 += wv * as_[c];
            s2 += wv * ad_[c];
        }
        wsrc1[i] = s1;
        wdst1[i] = s2;
        return;
    }
    b -= 2;
    if (b < 1) {  // wsrc2/wdst2
        int k = threadIdx.x;
        if (k < 128) {
            const float* wr = W2 + (size_t)k * 128;
            float s1 = 0.f, s2 = 0.f;
            for (int c = 0; c < 128; ++c) {
                float wv = wr[c];
                s1 += wv * as2v[c];
                s2 += wv * ad2v[c];
            }
            wsrc2[k] = s1;
            wdst2[k] = s2;
        }
        return;
    }
    b -= 1;
    {  // init cnt=1 (self-loop), slot head = self, zero as2/ad2
        int i = b * 256 + threadIdx.x;
        if (i < N) {
            cnt[i] = 1;
            slot[(size_t)i * MAXD] = i;
            as2[i] = 0.f;
            ad2[i] = 0.f;
        }
    }
}

// ---------------------- fused fill + alpha1 --------------------------------
// Blocks [0,Bfill): direct-slot fill, 4 edges/thread; all 4 returning
// atomics issued before any dependent store.
// Blocks [Bfill,...): alpha1 per node (1 wave/node, 4/block).
__launch_bounds__(256)
__global__ void fill_alpha_kernel(const int* __restrict__ src, const int* __restrict__ dst,
                                  int* __restrict__ cnt, int* __restrict__ slot, int E,
                                  const unsigned int* __restrict__ xrow,  // [N,64]
                                  const float* __restrict__ wsrc, const float* __restrict__ wdst,
                                  float* __restrict__ asrc, float* __restrict__ adst, int N,
                                  int Bfill) {
    if ((int)blockIdx.x < Bfill) {
        int i = (blockIdx.x * 256 + threadIdx.x) * 4;
        if (i + 3 < E) {
            int4 s4 = *(const int4*)&src[i];
            int4 d4 = *(const int4*)&dst[i];
            int p0 = atomicAdd(&cnt[d4.x], 1);
            int p1 = atomicAdd(&cnt[d4.y], 1);
            int p2 = atomicAdd(&cnt[d4.z], 1);
            int p3 = atomicAdd(&cnt[d4.w], 1);
            if (p0 < MAXD) slot[(size_t)d4.x * MAXD + p0] = s4.x;
            if (p1 < MAXD) slot[(size_t)d4.y * MAXD + p1] = s4.y;
            if (p2 < MAXD) slot[(size_t)d4.z * MAXD + p2] = s4.z;
            if (p3 < MAXD) slot[(size_t)d4.w * MAXD + p3] = s4.w;
        } else {
            for (; i < E; ++i) {
                int d = dst[i];
                int pos = atomicAdd(&cnt[d], 1);
                if (pos < MAXD) slot[(size_t)d * MAXD + pos] = src[i];
            }
        }
        return;
    }
    // ---- alpha1 (H=4) ----
    constexpr int H = 4;
    __shared__ float s_wv[2 * H * 128];
    for (int i = threadIdx.x; i < 2 * H * 128; i += 256)
        s_wv[i] = (i < H * 128) ? wsrc[i] : wdst[i - H * 128];
    __syncthreads();
    const int wid = threadIdx.x >> 6, lane = threadIdx.x & 63;
    const int n = (blockIdx.x - Bfill) * 4 + wid;
    if (n >= N) return;
    unsigned int u = xrow[(size_t)n * 64 + lane];
    float f0, f1;
    bf2x(u, f0, f1);
    float s1[H], s2[H];
#pragma unroll
    for (int h = 0; h < H; ++h) {
        float2 ws = *(const float2*)&s_wv[h * 128 + 2 * lane];
        float2 wd = *(const float2*)&s_wv[H * 128 + h * 128 + 2 * lane];
        s1[h] = f0 * ws.x + f1 * ws.y;
        s2[h] = f0 * wd.x + f1 * wd.y;
    }
#pragma unroll
    for (int off = 32; off; off >>= 1)
#pragma unroll
        for (int h = 0; h < H; ++h) {
            s1[h] += __shfl_xor(s1[h], off);
            s2[h] += __shfl_xor(s2[h], off);
        }
    if (lane == 0) {
#pragma unroll
        for (int h = 0; h < H; ++h) {
            asrc[(size_t)n * H + h] = s1[h];
            adst[(size_t)n * H + h] = s2[h];
        }
    }
}

// ---------------------------- x-space gather -------------------------------
// One wave per destination node; edges in slot[n*MAXD .. n*MAXD+deg).
// Quarter-wave (16 lanes x 16B) per 256B row: 4 edges per VMEM inst. Full
// batches = 8 k-iters (32 edges, 8KB in flight); tail via switch(kmax).
// float2 accumulation -> v_pk_fma_f32.
// launch_bounds(256,4): this kernel's live ranges need ~80 VGPRs; any
// tighter occupancy cap (e.g. (256,6), R15) spills ~155MB of scratch.
template <int H, int NPB>
__launch_bounds__(64 * NPB, 4)
__global__ void gat_gather_kernel(const uint4* __restrict__ xrow4,  // [N,16]
                                  const float* __restrict__ asrc,   // [N*H]
                                  const float* __restrict__ adst,   // [N*H]
                                  const int* __restrict__ cnt,      // [N] final degrees
                                  const int* __restrict__ slot,     // [N*MAXD]
                                  uint4* __restrict__ Sb4,          // [N, H*16]
                                  int N) {
    static_assert(H == 4 || H == 1, "H");
    const int wid = threadIdx.x >> 6, lane = threadIdx.x & 63;
    const int q = lane >> 4, l16 = lane & 15;
    const int n = blockIdx.x * NPB + wid;
    if (n >= N) return;

    __shared__ int s_src_all[NPB][64];
    __shared__ float s_w_all[NPB][64 * H];
    int* s_src = s_src_all[wid];
    float* s_w = s_w_all[wid];

    const int base = n * MAXD;
    const int deg = min(cnt[n], MAXD);  // >= 1 (self-loop)

    float adst_n[H];
#pragma unroll
    for (int h = 0; h < H; ++h) adst_n[h] = adst[(size_t)n * H + h];

    float sum_h[H] = {};
    v2f acc[4 * H];  // acc[h*4+j] = channels (l16*8+2j, +1), quarter-partial
#pragma unroll
    for (int i = 0; i < 4 * H; ++i) acc[i] = (v2f){0.f, 0.f};

    // batched gather body: KK k-iters, loads clustered before consumes.
    auto do_batch = [&](int j0, auto kc) {
        constexpr int KK = decltype(kc)::value;
        int ss[KK];
        uint4 d[KK];
#pragma unroll
        for (int k = 0; k < KK; ++k) ss[k] = s_src[j0 + k * 4 + q];
#pragma unroll
        for (int k = 0; k < KK; ++k) d[k] = xrow4[(size_t)ss[k] * 16 + l16];
#pragma unroll
        for (int k = 0; k < KK; ++k) {
            v2f f2[4];
            f2[0] = bf2p(d[k].x);
            f2[1] = bf2p(d[k].y);
            f2[2] = bf2p(d[k].z);
            f2[3] = bf2p(d[k].w);
            if constexpr (H == 4) {
                float4 w = *(const float4*)&s_w[(j0 + k * 4 + q) * 4];
                v2f w0 = (v2f){w.x, w.x}, w1 = (v2f){w.y, w.y};
                v2f w2 = (v2f){w.z, w.z}, w3 = (v2f){w.w, w.w};
#pragma unroll
                for (int j = 0; j < 4; ++j) {
                    acc[j] += w0 * f2[j];
                    acc[4 + j] += w1 * f2[j];
                    acc[8 + j] += w2 * f2[j];
                    acc[12 + j] += w3 * f2[j];
                }
            } else {
                float w = s_w[j0 + k * 4 + q];
                v2f w0 = (v2f){w, w};
#pragma unroll
                for (int j = 0; j < 4; ++j) acc[j] += w0 * f2[j];
            }
        }
    };

    for (int i0 = 0; i0 < deg; i0 += 64) {
        const int cntc = min(64, deg - i0);
        {  // branch-free prep: pad lanes use clamped source with weight 0
            const bool valid = lane < cntc;
            int idx = i0 + (valid ? lane : (cntc - 1));
            int s = slot[base + idx];
            s_src[lane] = s;
            if constexpr (H == 4) {
                float4 av = ((const float4*)asrc)[s];
                float ev[4] = {av.x, av.y, av.z, av.w};
#pragma unroll
                for (int hh = 0; hh < 4; ++hh) {
                    float e = ev[hh] + adst_n[hh];
                    e = e > 0.f ? e : 0.2f * e;
                    float wv = valid ? __expf(e) : 0.f;
                    s_w[lane * 4 + hh] = wv;
                    sum_h[hh] += wv;
                }
            } else {
                float e = asrc[s] + adst_n[0];
                e = e > 0.f ? e : 0.2f * e;
                float wv = valid ? __expf(e) : 0.f;
                s_w[lane] = wv;
                sum_h[0] += wv;
            }
        }
        __threadfence_block();  // drain LDS writes (same-wave cross-lane read)

        int j0 = 0;
        for (; j0 + 32 <= cntc; j0 += 32) do_batch(j0, IC<8>{});
        const int rem = cntc - j0;
        if (rem > 0) {
            // wave-uniform kmax; slots [cntc, j0+4*kmax) have weight 0 from prep
            switch ((rem + 3) >> 2) {
                case 1: do_batch(j0, IC<1>{}); break;
                case 2: do_batch(j0, IC<2>{}); break;
                case 3: do_batch(j0, IC<3>{}); break;
                case 4: do_batch(j0, IC<4>{}); break;
                case 5: do_batch(j0, IC<5>{}); break;
                case 6: do_batch(j0, IC<6>{}); break;
                case 7: do_batch(j0, IC<7>{}); break;
                default: do_batch(j0, IC<8>{}); break;
            }
        }
    }

    // cross-quarter reduce (lanes sharing l16): xor 16, 32
#pragma unroll
    for (int i = 0; i < 4 * H; ++i) {
        acc[i][0] += __shfl_xor(acc[i][0], 16);
        acc[i][1] += __shfl_xor(acc[i][1], 16);
        acc[i][0] += __shfl_xor(acc[i][0], 32);
        acc[i][1] += __shfl_xor(acc[i][1], 32);
    }
    // denominator full-wave reduce
#pragma unroll
    for (int off = 32; off; off >>= 1)
#pragma unroll
        for (int h = 0; h < H; ++h) sum_h[h] += __shfl_xor(sum_h[h], off);

    if constexpr (H == 4) {
#pragma unroll
        for (int h = 0; h < 4; ++h) {
            if (q == h) {  // quarter h writes head h (constant reg indices)
                float rd = 1.0f / sum_h[h];
                uint4 o;
                o.x = pack2(acc[h * 4 + 0][0] * rd, acc[h * 4 + 0][1] * rd);
                o.y = pack2(acc[h * 4 + 1][0] * rd, acc[h * 4 + 1][1] * rd);
                o.z = pack2(acc[h * 4 + 2][0] * rd, acc[h * 4 + 2][1] * rd);
                o.w = pack2(acc[h * 4 + 3][0] * rd, acc[h * 4 + 3][1] * rd);
                Sb4[(size_t)n * 64 + h * 16 + l16] = o;
            }
        }
    } else {
        if (q == 0) {
            float rd = 1.0f / sum_h[0];
            uint4 o;
            o.x = pack2(acc[0][0] * rd, acc[0][1] * rd);
            o.y = pack2(acc[1][0] * rd, acc[1][1] * rd);
            o.z = pack2(acc[2][0] * rd, acc[2][1] * rd);
            o.w = pack2(acc[3][0] * rd, acc[3][1] * rd);
            Sb4[(size_t)n * 16 + l16] = o;
        }
    }
}

// ---------------------------- MFMA GEMM + bias + act -----------------------
__device__ __forceinline__ void store_out(float* p, float v) { *p = v; }
__device__ __forceinline__ void store_out(unsigned short* p, float v) { *p = f2bf(v); }

// C = act(A @ Bt^T + bias). If FUSE_A2: also accumulate per-row dots
// as2[row] += sum_col val*ws2[col], ad2 likewise (alpha2 fused into gemm1).
template <typename OT, bool ELU, bool FUSE_A2>
__launch_bounds__(256)
__global__ void gemm_bias_act_kernel(const unsigned short* __restrict__ A,
                                     const unsigned short* __restrict__ Bt,
                                     const float* __restrict__ bias,
                                     OT* __restrict__ C,
                                     const float* __restrict__ ws2,
                                     const float* __restrict__ wd2,
                                     float* __restrict__ as2, float* __restrict__ ad2,
                                     int M, int Nout, int K) {
    constexpr int BK = 32;
    __shared__ unsigned short As[64][40];
    __shared__ unsigned short Bs[64][40];

    const int tid = threadIdx.x;
    const int w = tid >> 6;
    const int lane = tid & 63;
    const int m16 = lane & 15;
    const int kg = lane >> 4;
    const int m0 = blockIdx.y * 64;
    const int n0 = blockIdx.x * 64;

    v4f acc[4];
#pragma unroll
    for (int i = 0; i < 4; ++i) acc[i] = (v4f){0.f, 0.f, 0.f, 0.f};

    const int srow = tid >> 2;
    const int sseg = tid & 3;
    const int arow_g = min(m0 + srow, M - 1);  // clamp; tail rows never stored
    const unsigned short* Ap = &A[(size_t)arow_g * K + sseg * 8];
    const unsigned short* Bp = &Bt[(size_t)(n0 + srow) * K + sseg * 8];

    for (int k0 = 0; k0 < K; k0 += BK) {
        uint4 av = *(const uint4*)(Ap + k0);
        uint4 bv = *(const uint4*)(Bp + k0);
        __syncthreads();
        *(uint4*)&As[srow][sseg * 8] = av;
        *(uint4*)&Bs[srow][sseg * 8] = bv;
        __syncthreads();
        v8s a = *(const v8s*)&As[w * 16 + m16][kg * 8];
#pragma unroll
        for (int i = 0; i < 4; ++i) {
            v8s b = *(const v8s*)&Bs[i * 16 + m16][kg * 8];
            acc[i] = __builtin_amdgcn_mfma_f32_16x16x32_bf16(a, b, acc[i], 0, 0, 0);
        }
    }

    float pr_s[4] = {}, pr_d[4] = {};
#pragma unroll
    for (int i = 0; i < 4; ++i) {
        const int col = n0 + i * 16 + m16;
        const float bv = bias[col];
        float w2s = 0.f, w2d = 0.f;
        if constexpr (FUSE_A2) {
            w2s = ws2[col];
            w2d = wd2[col];
        }
#pragma unroll
        for (int r = 0; r < 4; ++r) {
            int row = m0 + w * 16 + kg * 4 + r;
            if (row < M) {
                float val = acc[i][r] + bv;
                if constexpr (ELU) val = val > 0.f ? val : (__expf(val) - 1.0f);
                store_out(&C[(size_t)row * Nout + col], val);
                if constexpr (FUSE_A2) {
                    pr_s[r] += val * w2s;
                    pr_d[r] += val * w2d;
                }
            }
        }
    }
    if constexpr (FUSE_A2) {
        // reduce across the 16 lanes sharing a row (m16 axis, within quarter)
#pragma unroll
        for (int off = 1; off < 16; off <<= 1)
#pragma unroll
            for (int r = 0; r < 4; ++r) {
                pr_s[r] += __shfl_xor(pr_s[r], off);
                pr_d[r] += __shfl_xor(pr_d[r], off);
            }
        if (m16 == 0) {
#pragma unroll
            for (int r = 0; r < 4; ++r) {
                int row = m0 + w * 16 + kg * 4 + r;
                if (row < M) {
                    atomicAdd(&as2[row], pr_s[r]);
                    atomicAdd(&ad2[row], pr_d[r]);
                }
            }
        }
    }
}

// ---------------------------------------------------------------------------

extern "C" void kernel_launch(void* const* d_in, const int* in_sizes, int n_in,
                              void* d_out, int out_size, void* d_ws, size_t ws_size,
                              hipStream_t stream) {
    const float* x = (const float*)d_in[0];
    const float* W1 = (const float*)d_in[1];
    const float* a_src1 = (const float*)d_in[2];
    const float* a_dst1 = (const float*)d_in[3];
    const float* b1 = (const float*)d_in[4];
    const float* W2 = (const float*)d_in[5];
    const float* a_src2 = (const float*)d_in[6];
    const float* a_dst2 = (const float*)d_in[7];
    const float* b2 = (const float*)d_in[8];
    const int* edge = (const int*)d_in[9];
    float* out = (float*)d_out;

    constexpr int F = 128, H = 4;
    const int N = in_sizes[0] / F;  // 20000
    const int E = in_sizes[9] / 2;  // 640000

    char* ws = (char*)d_ws;
    size_t o = 0;
    auto take = [&](size_t bytes) {
        char* p = ws + o;
        o = (o + bytes + 255) & ~(size_t)255;
        return p;
    };
    int* cnt = (int*)take((size_t)N * 4);
    int* slot = (int*)take((size_t)N * MAXD * 4);                       // 10.2 MB
    unsigned short* xb = (unsigned short*)take((size_t)N * F * 2);      // bf16 x
    unsigned short* Bt1 = (unsigned short*)take((size_t)F * H * F * 2); // [128][512]
    unsigned short* Bt2 = (unsigned short*)take((size_t)F * F * 2);     // [128][128]
    float* wsrc1 = (float*)take((size_t)H * F * 4);
    float* wdst1 = (float*)take((size_t)H * F * 4);
    float* wsrc2 = (float*)take((size_t)F * 4);
    float* wdst2 = (float*)take((size_t)F * 4);
    float* as1 = (float*)take((size_t)N * H * 4);
    float* ad1 = (float*)take((size_t)N * H * 4);
    unsigned short* Sb1 = (unsigned short*)take((size_t)N * H * F * 2);  // [N,512] bf16
    unsigned short* h2b = (unsigned short*)take((size_t)N * F * 2);      // layer-1 out, bf16
    float* as2 = (float*)take((size_t)N * 4);
    float* ad2 = (float*)take((size_t)N * 4);
    unsigned short* S2b = (unsigned short*)take((size_t)N * F * 2);      // [N,128] bf16
    (void)ws_size;

    const int* esrc = edge;
    const int* edst = edge + E;

    // ---- fused prep (casts, weight transforms, cnt=1/self-loop, zero a2) ----
    const int Bcast = (N * 32 + 255) / 256;
    const int Bzero = (N + 255) / 256;
    hipLaunchKernelGGL(fused_prep_kernel, dim3(Bcast + 256 + 64 + 2 + 1 + Bzero), dim3(256), 0,
                       stream, x, W1, W2, a_src1, a_dst1, a_src2, a_dst2, xb, Bt1, Bt2, wsrc1,
                       wdst1, wsrc2, wdst2, cnt, slot, as2, ad2, N);

    // ---- fused direct-slot fill (4 edges/thread) + alpha1 ----
    const int Bfill = (E / 4 + 255) / 256;
    const int Balpha = (N + 3) / 4;
    hipLaunchKernelGGL(fill_alpha_kernel, dim3(Bfill + Balpha), dim3(256), 0, stream, esrc, edst,
                       cnt, slot, E, (const unsigned int*)xb, wsrc1, wdst1, as1, ad1, N, Bfill);

    // ---- layer 1: gather + gemm (alpha2 fused into epilogue) ----
    hipLaunchKernelGGL((gat_gather_kernel<H, 4>), dim3((N + 3) / 4), dim3(256), 0, stream,
                       (const uint4*)xb, as1, ad1, cnt, slot, (uint4*)Sb1, N);
    hipLaunchKernelGGL((gemm_bias_act_kernel<unsigned short, true, true>),
                       dim3(F / 64, (N + 63) / 64), dim3(256), 0, stream, Sb1, Bt1, b1, h2b,
                       wsrc2, wdst2, as2, ad2, N, F, H * F);

    // ---- layer 2: gather + gemm ----
    hipLaunchKernelGGL((gat_gather_kernel<1, 4>), dim3((N + 3) / 4), dim3(256), 0, stream,
                       (const uint4*)h2b, as2, ad2, cnt, slot, (uint4*)S2b, N);
    hipLaunchKernelGGL((gemm_bias_act_kernel<float, true, false>), dim3(F / 64, (N + 63) / 64),
                       dim3(256), 0, stream, S2b, Bt2, b2, out, nullptr, nullptr, nullptr,
                       nullptr, N, F, F);
}